// Round 7
// baseline (12496.342 us; speedup 1.0000x reference)
//
#include <hip/hip_runtime.h>
#include <math.h>

// Problem constants (reference: B,T,D,H = 32,2048,512,512)
#define BB   32
#define TT   2048
#define DD   512
#define HH   512
#define G4H  2048   // 4*H

static __device__ __forceinline__ float rl(float v, int l) {
    return __int_as_float(__builtin_amdgcn_readlane(__float_as_int(v), l));
}

// ---------------------------------------------------------------------------
// Phase A: xw[t_local*32 + b][col] = sum_d X[b][t0+t][d] * W[d][col] + bias[col]
// fp32 tiled GEMM: 128x128 block tile, 16 K-step, 256 threads, 8x8 microtile.
// Also zeroes the 8 group barrier counters on the first chunk (t0==0).
// ---------------------------------------------------------------------------
__global__ __launch_bounds__(256, 2) void gemm_xw(
    const float* __restrict__ X, const float* __restrict__ Wm,
    const float* __restrict__ bias, float* __restrict__ xw,
    int t0, unsigned int* __restrict__ ctr)
{
    if (t0 == 0 && blockIdx.x == 0 && blockIdx.y == 0 && threadIdx.x < 8)
        ctr[threadIdx.x * 64] = 0u;

    __shared__ float As[16][128];
    __shared__ float Bs[16][128];

    const int tid  = threadIdx.x;
    const int row0 = blockIdx.y * 128;   // rows: (t_local, b) t-major
    const int col0 = blockIdx.x * 128;
    const int tx = tid & 15;
    const int ty = tid >> 4;

    float acc[8][8];
    #pragma unroll
    for (int i = 0; i < 8; ++i)
        #pragma unroll
        for (int j = 0; j < 8; ++j) acc[i][j] = 0.f;

    for (int k0 = 0; k0 < DD; k0 += 16) {
        #pragma unroll
        for (int i = 0; i < 2; ++i) {
            int qa = tid + i * 256;          // 0..511 quads
            int r  = qa >> 2, kq = qa & 3;
            int grow = row0 + r;
            int b = grow & 31, tl = grow >> 5;
            const float4 a = *(const float4*)(X + ((size_t)b * TT + t0 + tl) * DD + k0 + kq * 4);
            As[kq*4+0][r] = a.x; As[kq*4+1][r] = a.y;
            As[kq*4+2][r] = a.z; As[kq*4+3][r] = a.w;

            int qb = tid + i * 256;
            int kb = qb >> 5, c4 = qb & 31;
            *(float4*)&Bs[kb][c4*4] =
                *(const float4*)(Wm + (size_t)(k0 + kb) * G4H + col0 + c4 * 4);
        }
        __syncthreads();

        #pragma unroll
        for (int k = 0; k < 16; ++k) {
            float a[8], b[8];
            #pragma unroll
            for (int i = 0; i < 8; ++i) a[i] = As[k][ty*8 + i];
            #pragma unroll
            for (int j = 0; j < 8; ++j) b[j] = Bs[k][tx*8 + j];
            #pragma unroll
            for (int i = 0; i < 8; ++i)
                #pragma unroll
                for (int j = 0; j < 8; ++j) acc[i][j] += a[i] * b[j];
        }
        __syncthreads();
    }

    #pragma unroll
    for (int i = 0; i < 8; ++i) {
        int grow = row0 + ty*8 + i;
        float* dst = xw + (size_t)grow * G4H + col0 + tx*8;
        #pragma unroll
        for (int j = 0; j < 8; j += 4) {
            float4 v;
            v.x = acc[i][j+0] + bias[col0 + tx*8 + j + 0];
            v.y = acc[i][j+1] + bias[col0 + tx*8 + j + 1];
            v.z = acc[i][j+2] + bias[col0 + tx*8 + j + 2];
            v.w = acc[i][j+3] + bias[col0 + tx*8 + j + 3];
            *(float4*)(dst + j) = v;
        }
    }
}

// ---------------------------------------------------------------------------
// Phase B: persistent recurrent kernel, LDS-resident weights, readlane dot.
// Grid = 256 blocks x 256 threads. p = blockIdx%8 (batches 4p..4p+3),
// q = blockIdx/8 (hidden units 16q..16q+15 -> 64 gate columns, col_local=lane).
// Wave w (0..3) = K-slice of 128 (compute) = batch (reduce/update).
//
// Dot restructure this round: h comes in via per-wave REGISTERS, not LDS.
// Each wave loads h[b][w*128 + lane*2 + r] (float2 per batch, coalesced,
// relaxed system-scope) and the k-walk broadcasts h values through
// v_readlane (SALU pipe, compile-time lane index) into the FMA's single
// allowed SGPR operand. This removes all 128 wave-uniform broadcast
// ds_read_b128 per wave per step (the suspected LDS-pipe bottleneck) and
// the h-staging __syncthreads. Only the 32 per-lane wlds reads remain on
// the LDS pipe. Sync protocol unchanged from R6 (relaxed system at L3).
// ---------------------------------------------------------------------------
__global__ __launch_bounds__(256, 1) void lstm_rec(
    const float* __restrict__ W,
    const float* __restrict__ h_init,
    const float* __restrict__ xw,
    float* out,
    float* __restrict__ c_ws,
    unsigned int* ctr,
    int t0, int nT)
{
    __shared__ float4 wlds[128][64];    // [k>>2][col_local] = w[4k..4k+3][col]
    __shared__ float  red[4][4][64];    // [kslice-wave][batch][lane]

    const int tid  = threadIdx.x;
    const int p    = blockIdx.x & 7;
    const int q    = blockIdx.x >> 3;
    const int w    = tid >> 6;          // wave id = K-slice (compute) = batch (reduce)
    const int lane = tid & 63;
    const int gi   = lane >> 4;
    const int u    = lane & 15;
    const int col  = gi * HH + q * 16 + u;   // this lane's global gate column

    // One-time: stage this block's recurrent W slice into LDS, k-packed.
    {
        const int cc = tid & 63;
        const int kq = tid >> 6;
        const int cg = (cc >> 4) * HH + q * 16 + (cc & 15);  // global col of cc
        const float* Wr = W + (size_t)DD * G4H + cg;
        #pragma unroll 4
        for (int i = 0; i < 32; ++i) {
            const int k4 = i * 4 + kq;          // 0..127
            float4 v;
            v.x = Wr[(size_t)(4 * k4 + 0) * G4H];
            v.y = Wr[(size_t)(4 * k4 + 1) * G4H];
            v.z = Wr[(size_t)(4 * k4 + 2) * G4H];
            v.w = Wr[(size_t)(4 * k4 + 3) * G4H];
            wlds[k4][cc] = v;
        }
    }
    __syncthreads();

    // c state: lanes 0..15 of wave w hold c[batch 4p+w][unit q*16+lane]
    float c = 0.f;
    if (t0 > 0 && lane < 16)
        c = c_ws[(size_t)(4 * p + w) * HH + q * 16 + lane];

    unsigned int* myctr = ctr + p * 64;
    const int k4b = w * 32;               // this wave's k-slice, in float4 units
    const int hoff = w * 128 + lane * 2;  // this lane's h elements (k-slice)

    // Prologue: load xw for step 0.
    float xg = xw[((size_t)0 * BB + 4 * p + w) * G4H + col];

    for (int t = 0; t < nT; ++t) {
        const int gt = t0 + t;

        // Prefetch next step's x-part NOW (~one full step of latency cover).
        float xg_next = 0.f;
        if (t + 1 < nT)
            xg_next = xw[((size_t)(t + 1) * BB + 4 * p + w) * G4H + col];

        // Load this wave's h k-slice for 4 batches into registers.
        // hreg[b] = { h[b][hoff], h[b][hoff+1] }; relaxed system scope reads
        // fresh L3 (no acquire needed, barrier at loop end ordered us).
        float2 hr0, hr1, hr2, hr3;
        if (gt == 0) {
            const float2 hv = *(const float2*)(h_init + hoff);
            hr0 = hv; hr1 = hv; hr2 = hv; hr3 = hv;
        } else {
            const float* o0 = &out[((size_t)(4 * p + 0) * TT + (gt - 1)) * HH + hoff];
            const float* o1 = &out[((size_t)(4 * p + 1) * TT + (gt - 1)) * HH + hoff];
            const float* o2 = &out[((size_t)(4 * p + 2) * TT + (gt - 1)) * HH + hoff];
            const float* o3 = &out[((size_t)(4 * p + 3) * TT + (gt - 1)) * HH + hoff];
            hr0.x = __hip_atomic_load(o0 + 0, __ATOMIC_RELAXED, __HIP_MEMORY_SCOPE_SYSTEM);
            hr0.y = __hip_atomic_load(o0 + 1, __ATOMIC_RELAXED, __HIP_MEMORY_SCOPE_SYSTEM);
            hr1.x = __hip_atomic_load(o1 + 0, __ATOMIC_RELAXED, __HIP_MEMORY_SCOPE_SYSTEM);
            hr1.y = __hip_atomic_load(o1 + 1, __ATOMIC_RELAXED, __HIP_MEMORY_SCOPE_SYSTEM);
            hr2.x = __hip_atomic_load(o2 + 0, __ATOMIC_RELAXED, __HIP_MEMORY_SCOPE_SYSTEM);
            hr2.y = __hip_atomic_load(o2 + 1, __ATOMIC_RELAXED, __HIP_MEMORY_SCOPE_SYSTEM);
            hr3.x = __hip_atomic_load(o3 + 0, __ATOMIC_RELAXED, __HIP_MEMORY_SCOPE_SYSTEM);
            hr3.y = __hip_atomic_load(o3 + 1, __ATOMIC_RELAXED, __HIP_MEMORY_SCOPE_SYSTEM);
        }

        // K-slice dot via readlane broadcast: k = 4j+m, lane_src = 2j+(m>>1),
        // component = m&1. 512 readlane (SALU) + 512 FMA (VALU), 32 LDS reads.
        float a0 = 0.f, a1 = 0.f, a2 = 0.f, a3 = 0.f;
        #pragma unroll
        for (int j = 0; j < 32; ++j) {
            const float4 wv = wlds[k4b + j][lane];   // per-lane b128, no conflict
            const int l0 = 2 * j, l1 = 2 * j + 1;
            a0 += rl(hr0.x, l0) * wv.x; a0 += rl(hr0.y, l0) * wv.y;
            a0 += rl(hr0.x, l1) * wv.z; a0 += rl(hr0.y, l1) * wv.w;
            a1 += rl(hr1.x, l0) * wv.x; a1 += rl(hr1.y, l0) * wv.y;
            a1 += rl(hr1.x, l1) * wv.z; a1 += rl(hr1.y, l1) * wv.w;
            a2 += rl(hr2.x, l0) * wv.x; a2 += rl(hr2.y, l0) * wv.y;
            a2 += rl(hr2.x, l1) * wv.z; a2 += rl(hr2.y, l1) * wv.w;
            a3 += rl(hr3.x, l0) * wv.x; a3 += rl(hr3.y, l0) * wv.y;
            a3 += rl(hr3.x, l1) * wv.z; a3 += rl(hr3.y, l1) * wv.w;
        }

        red[w][0][lane] = a0; red[w][1][lane] = a1;
        red[w][2][lane] = a2; red[w][3][lane] = a3;
        __syncthreads();

        // Wave w reduces batch w across the 4 K-slices, adds x-part (+bias).
        float g = red[0][w][lane] + red[1][w][lane]
                + red[2][w][lane] + red[3][w][lane] + xg;

        // Gather f,i,o,g for unit ul; lanes 0..15 do the elementwise update.
        const int ul = lane & 15;
        const float fv = __shfl(g, ul);
        const float iv = __shfl(g, ul + 16);
        const float ov = __shfl(g, ul + 32);
        const float gv = __shfl(g, ul + 48);
        if (lane < 16) {
            const float sf = 1.f / (1.f + __expf(-fv));
            const float si = 1.f / (1.f + __expf(-iv));
            const float so = 1.f / (1.f + __expf(-ov));
            const float tg = 1.f - 2.f / (__expf(2.f * gv) + 1.f);
            c = sf * c + si * tg;
            const float tc = 1.f - 2.f / (__expf(2.f * c) + 1.f);
            const float h = so * tc;
            // System-scope relaxed store: lands at L3, visible to all XCDs,
            // no wbl2 cache walk.
            __hip_atomic_store(
                &out[((size_t)(4 * p + w) * TT + gt) * HH + q * 16 + lane],
                h, __ATOMIC_RELAXED, __HIP_MEMORY_SCOPE_SYSTEM);
        }

        // Per-group barrier, 32 blocks, zero cache-maintenance:
        // __syncthreads drains every wave's system-scope h stores (vmcnt(0)
        // -> ack'd at L3), then tid0 bumps the group counter (relaxed
        // system RMW at L3) and spins on relaxed system loads.
        __syncthreads();
        if (tid == 0) {
            __hip_atomic_fetch_add(myctr, 1u, __ATOMIC_RELAXED, __HIP_MEMORY_SCOPE_SYSTEM);
            const unsigned int tgt = 32u * (unsigned int)(gt + 1);
            while (__hip_atomic_load(myctr, __ATOMIC_RELAXED, __HIP_MEMORY_SCOPE_SYSTEM) < tgt) {}
        }
        // Compiler-level fence only (no HW op): keeps next step's h loads
        // from being hoisted above the spin.
        asm volatile("" ::: "memory");
        __syncthreads();

        xg = xg_next;
    }

    // Spill c state for the next chunk (read at next dispatch; kernel
    // boundary provides the coherence).
    if (lane < 16)
        c_ws[(size_t)(4 * p + w) * HH + q * 16 + lane] = c;
}

// ---------------------------------------------------------------------------
extern "C" void kernel_launch(void* const* d_in, const int* in_sizes, int n_in,
                              void* d_out, int out_size, void* d_ws, size_t ws_size,
                              hipStream_t stream) {
    const float* x      = (const float*)d_in[0];
    // d_in[1] = input_paddings (unused)
    const float* W      = (const float*)d_in[2];
    const float* bias   = (const float*)d_in[3];
    const float* h_init = (const float*)d_in[4];
    float* out = (float*)d_out;

    // Pick the largest chunk of T whose xw buffer fits in ws
    // (xw chunk = CT*32*2048*4 bytes; + 2KB counters + 64KB c-state).
    static const int cand[] = {2048, 1024, 512, 256, 128, 64, 32, 16, 8, 4};
    int CT = 4;
    for (int i = 0; i < 10; ++i) {
        if ((size_t)cand[i] * BB * G4H * 4 + 2048 + 65536 <= ws_size) { CT = cand[i]; break; }
    }
    const size_t xw_bytes = (size_t)CT * BB * G4H * 4;
    float*        xw   = (float*)d_ws;
    unsigned int* ctr  = (unsigned int*)((char*)d_ws + xw_bytes);
    float*        c_ws = (float*)((char*)d_ws + xw_bytes + 2048);

    for (int t0 = 0; t0 < TT; t0 += CT) {
        dim3 g(G4H / 128, CT * BB / 128);
        gemm_xw<<<g, 256, 0, stream>>>(x, W, bias, xw, t0, ctr);
        lstm_rec<<<256, 256, 0, stream>>>(W, h_init, xw, out, c_ws, ctr, t0, CT);
    }
}